// Round 1
// baseline (404.796 us; speedup 1.0000x reference)
//
#include <hip/hip_runtime.h>
#include <hip/hip_fp16.h>

typedef _Float16 f16x8 __attribute__((ext_vector_type(8)));
typedef float    f32x4 __attribute__((ext_vector_type(4)));

constexpr int Nn = 8192;
constexpr int Dd = 256;
constexpr int JB = 1024;   // K-chunk per block in the main GEMM-reduce

// ---------------------------------------------------------------------------
// K1: row sums of A -> dis[i] = rsqrt(sum+1e-10)  (d_inv_sqrt)
//                      rd[i]  = sqrt(sum+1e-10)   (1/dis, for reconstructing Zn)
// One wave per row, float4 coalesced loads.
__global__ __launch_bounds__(256) void k_rowsum(const float* __restrict__ A,
                                                float* __restrict__ dis,
                                                float* __restrict__ rd) {
    const int row  = blockIdx.x * 4 + (threadIdx.x >> 6);
    const int lane = threadIdx.x & 63;
    const float4* rp = reinterpret_cast<const float4*>(A + (size_t)row * Nn);
    float s = 0.f;
    #pragma unroll
    for (int i = 0; i < Nn / 256; ++i) {          // 32 iterations
        float4 v = rp[i * 64 + lane];
        s += (v.x + v.y) + (v.z + v.w);
    }
    #pragma unroll
    for (int off = 32; off > 0; off >>= 1) s += __shfl_down(s, off, 64);
    if (lane == 0) {
        float rs = s + 1e-10f;
        dis[row] = rsqrtf(rs);
        rd[row]  = sqrtf(rs);
    }
}

// ---------------------------------------------------------------------------
// K2: Zn = Z / max(||Z_row||,1e-12); Y = dis*Zn; store TRANSPOSED Yt[256][8192] f16
// Block = 256 threads handles 64 rows; LDS transpose for coalesced-ish output.
__global__ __launch_bounds__(256) void k_makeYt(const float* __restrict__ Z,
                                                const float* __restrict__ dis,
                                                _Float16* __restrict__ Yt) {
    __shared__ float nrm[64][4];
    __shared__ _Float16 tile[Dd][72];   // +8 pad: row stride 144B breaks bank aliasing
    const int t = threadIdx.x;
    const int r = t >> 2, q = t & 3;
    const int row = blockIdx.x * 64 + r;
    const float4* zp = reinterpret_cast<const float4*>(Z + (size_t)row * Dd + q * 64);
    float4 v[16];
    float ss = 0.f;
    #pragma unroll
    for (int i = 0; i < 16; ++i) {
        v[i] = zp[i];
        ss += v[i].x*v[i].x + v[i].y*v[i].y + v[i].z*v[i].z + v[i].w*v[i].w;
    }
    nrm[r][q] = ss;
    __syncthreads();
    const float tot   = nrm[r][0] + nrm[r][1] + nrm[r][2] + nrm[r][3];
    const float scale = dis[row] / fmaxf(sqrtf(tot), 1e-12f);
    #pragma unroll
    for (int i = 0; i < 16; ++i) {
        const int c0 = q * 64 + i * 4;
        tile[c0+0][r] = (_Float16)(v[i].x * scale);
        tile[c0+1][r] = (_Float16)(v[i].y * scale);
        tile[c0+2][r] = (_Float16)(v[i].z * scale);
        tile[c0+3][r] = (_Float16)(v[i].w * scale);
    }
    __syncthreads();
    // thread t writes Yt row k=t, cols [blk*64, blk*64+64): 128B contiguous
    int4*       dst = reinterpret_cast<int4*>(Yt + (size_t)t * Nn + blockIdx.x * 64);
    const int4* src = reinterpret_cast<const int4*>(&tile[t][0]);
    #pragma unroll
    for (int i = 0; i < 8; ++i) dst[i] = src[i];
}

// ---------------------------------------------------------------------------
// K2b: s[k] = sum_j Zn[j][k] = sum_j Yt[k][j] * rd[j]   (one block per k)
__global__ __launch_bounds__(256) void k_colsum(const _Float16* __restrict__ Yt,
                                                const float* __restrict__ rd,
                                                float* __restrict__ s) {
    const int k = blockIdx.x;
    const int t = threadIdx.x;
    const _Float16* yp = Yt + (size_t)k * Nn + t * 32;
    const float*    rp = rd + t * 32;
    float acc = 0.f;
    #pragma unroll
    for (int i = 0; i < 32; ++i) acc += (float)yp[i] * rp[i];
    #pragma unroll
    for (int off = 32; off > 0; off >>= 1) acc += __shfl_down(acc, off, 64);
    __shared__ float red[4];
    if ((t & 63) == 0) red[t >> 6] = acc;
    __syncthreads();
    if (t == 0) s[k] = red[0] + red[1] + red[2] + red[3];
}

// ---------------------------------------------------------------------------
// K3: T += sum_{i in I} Y_i . (A[I, Jchunk] @ Y[Jchunk])  via f16 MFMA.
// Block: 256 thr = 4 waves; 16-row I-tile; each wave owns 64 of the 256 N-cols
// (4 MFMA n-tiles). A converted f32->f16 in-register; B frags are contiguous
// 16B loads from Yt (L2-resident, 4 MB).
// MFMA 16x16x32_f16 layouts: A: row=l&15, k=(l>>4)*8+e ; B: col=l&15, same k ;
// D: col=l&15, row=(l>>4)*4+r  [measured m89/m91].
__global__ __launch_bounds__(256) void k_main(const float* __restrict__ A,
                                              const _Float16* __restrict__ Yt,
                                              float* __restrict__ T) {
    const int ib = blockIdx.x & (Nn / 16 - 1);      // 512 I-tiles
    const int jb = blockIdx.x >> 9;                 // 8192/JB J-chunks
    const int I0 = ib * 16;
    const int J0 = jb * JB;
    const int w  = threadIdx.x >> 6;
    const int l  = threadIdx.x & 63;
    const int lr = l & 15;
    const int lk = l >> 4;

    f32x4 acc[4] = {{0,0,0,0},{0,0,0,0},{0,0,0,0},{0,0,0,0}};

    const float*    abase = A  + (size_t)(I0 + lr) * Nn + J0 + lk * 8;
    const _Float16* ybase = Yt + J0 + lk * 8;
    const int n0 = w * 64 + lr;

    for (int jj = 0; jj < JB; jj += 32) {
        const float4* ap = reinterpret_cast<const float4*>(abase + jj);
        const float4 a0 = ap[0];
        const float4 a1 = ap[1];
        const f16x8 af = { (_Float16)a0.x, (_Float16)a0.y, (_Float16)a0.z, (_Float16)a0.w,
                           (_Float16)a1.x, (_Float16)a1.y, (_Float16)a1.z, (_Float16)a1.w };
        #pragma unroll
        for (int tn = 0; tn < 4; ++tn) {
            const f16x8 bf = *reinterpret_cast<const f16x8*>(ybase + (size_t)(n0 + tn*16) * Nn + jj);
            acc[tn] = __builtin_amdgcn_mfma_f32_16x16x32_f16(af, bf, acc[tn], 0, 0, 0);
        }
    }

    // epilogue: part = sum over held W[i][n] * Y[i][n]
    float part = 0.f;
    #pragma unroll
    for (int tn = 0; tn < 4; ++tn) {
        const int n = w * 64 + tn * 16 + lr;
        #pragma unroll
        for (int r = 0; r < 4; ++r) {
            const int i = I0 + lk * 4 + r;
            part += acc[tn][r] * (float)Yt[(size_t)n * Nn + i];
        }
    }
    #pragma unroll
    for (int off = 32; off > 0; off >>= 1) part += __shfl_down(part, off, 64);
    __shared__ float red[4];
    if (l == 0) red[w] = part;
    __syncthreads();
    if (threadIdx.x == 0) atomicAdd(T, red[0] + red[1] + red[2] + red[3]);
}

// ---------------------------------------------------------------------------
// K4: out[0] = homo = -T ; out[1] = hetero = ||s||^2 - T
__global__ __launch_bounds__(256) void k_final(const float* __restrict__ s,
                                               const float* __restrict__ T,
                                               float* __restrict__ out) {
    const int t = threadIdx.x;
    float v = s[t];
    float p = v * v;
    #pragma unroll
    for (int off = 32; off > 0; off >>= 1) p += __shfl_down(p, off, 64);
    __shared__ float red[4];
    if ((t & 63) == 0) red[t >> 6] = p;
    __syncthreads();
    if (t == 0) {
        const float ss = red[0] + red[1] + red[2] + red[3];
        const float Tv = *T;
        out[0] = -Tv;
        out[1] = ss - Tv;
    }
}

// ---------------------------------------------------------------------------
extern "C" void kernel_launch(void* const* d_in, const int* in_sizes, int n_in,
                              void* d_out, int out_size, void* d_ws, size_t ws_size,
                              hipStream_t stream) {
    const float* Z = (const float*)d_in[1];
    const float* A = (const float*)d_in[2];
    float* out = (float*)d_out;

    char* ws = (char*)d_ws;
    float*    dis = (float*)(ws);               // 32 KB
    float*    rd  = (float*)(ws + 32768);       // 32 KB
    float*    s   = (float*)(ws + 65536);       // 1 KB
    float*    T   = (float*)(ws + 66560);       // 4 B (atomic accumulator)
    _Float16* Yt  = (_Float16*)(ws + 131072);   // 256*8192*2 = 4 MB

    hipMemsetAsync(T, 0, sizeof(float), stream);   // ws is poisoned 0xAA; zero T each call
    k_rowsum<<<Nn / 4, 256, 0, stream>>>(A, dis, rd);
    k_makeYt<<<Nn / 64, 256, 0, stream>>>(Z, dis, Yt);
    k_colsum<<<Dd, 256, 0, stream>>>(Yt, rd, s);
    k_main<<<(Nn / 16) * (Nn / JB), 256, 0, stream>>>(A, Yt, T);
    k_final<<<1, 256, 0, stream>>>(s, T, out);
}

// Round 2
// 153.061 us; speedup vs baseline: 2.6447x; 2.6447x over previous
//
#include <hip/hip_runtime.h>
#include <hip/hip_fp16.h>

typedef _Float16 f16x8 __attribute__((ext_vector_type(8)));
typedef _Float16 f16x4 __attribute__((ext_vector_type(4)));
typedef float    f32x4 __attribute__((ext_vector_type(4)));

constexpr int Nn = 8192;
constexpr int Dd = 256;

constexpr int BM = 64;     // I-rows per block
constexpr int KC = 1024;   // K range per block
constexpr int SK = 128;    // staged K subchunk (LDS: 256 n x 128 k f16 = 64 KB)

// ---------------------------------------------------------------------------
// K1: row sums of A -> dis[i] = rsqrt(sum+1e-10), rd[i] = sqrt(sum+1e-10)
__global__ __launch_bounds__(256) void k_rowsum(const float* __restrict__ A,
                                                float* __restrict__ dis,
                                                float* __restrict__ rd) {
    const int row  = blockIdx.x * 4 + (threadIdx.x >> 6);
    const int lane = threadIdx.x & 63;
    const float4* rp = reinterpret_cast<const float4*>(A + (size_t)row * Nn);
    float s = 0.f;
    #pragma unroll
    for (int i = 0; i < Nn / 256; ++i) {
        float4 v = rp[i * 64 + lane];
        s += (v.x + v.y) + (v.z + v.w);
    }
    #pragma unroll
    for (int off = 32; off > 0; off >>= 1) s += __shfl_down(s, off, 64);
    if (lane == 0) {
        float rs = s + 1e-10f;
        dis[row] = rsqrtf(rs);
        rd[row]  = sqrtf(rs);
    }
}

// ---------------------------------------------------------------------------
// K2: Y = dis * Z/||Z||; store Yt[256 n][8192 i] (k-major, for staging/colsum)
//     and Yr[8192 i][256 n] (row-major, for the epilogue dot)
__global__ __launch_bounds__(256) void k_makeYt(const float* __restrict__ Z,
                                               const float* __restrict__ dis,
                                               _Float16* __restrict__ Yt,
                                               _Float16* __restrict__ Yr) {
    __shared__ float nrm[64][4];
    __shared__ _Float16 tile[Dd][72];
    const int t = threadIdx.x;
    const int r = t >> 2, q = t & 3;
    const int row = blockIdx.x * 64 + r;
    const float4* zp = reinterpret_cast<const float4*>(Z + (size_t)row * Dd + q * 64);
    float4 v[16];
    float ss = 0.f;
    #pragma unroll
    for (int i = 0; i < 16; ++i) {
        v[i] = zp[i];
        ss += v[i].x*v[i].x + v[i].y*v[i].y + v[i].z*v[i].z + v[i].w*v[i].w;
    }
    nrm[r][q] = ss;
    __syncthreads();
    const float tot   = nrm[r][0] + nrm[r][1] + nrm[r][2] + nrm[r][3];
    const float scale = dis[row] / fmaxf(sqrtf(tot), 1e-12f);
    #pragma unroll
    for (int i = 0; i < 16; ++i) {
        const int c0 = q * 64 + i * 4;
        f16x4 y = { (_Float16)(v[i].x * scale), (_Float16)(v[i].y * scale),
                    (_Float16)(v[i].z * scale), (_Float16)(v[i].w * scale) };
        tile[c0+0][r] = y[0];
        tile[c0+1][r] = y[1];
        tile[c0+2][r] = y[2];
        tile[c0+3][r] = y[3];
        *reinterpret_cast<f16x4*>(Yr + (size_t)row * Dd + c0) = y;
    }
    __syncthreads();
    int4*       dst = reinterpret_cast<int4*>(Yt + (size_t)t * Nn + blockIdx.x * 64);
    const int4* src = reinterpret_cast<const int4*>(&tile[t][0]);
    #pragma unroll
    for (int i = 0; i < 8; ++i) dst[i] = src[i];
}

// ---------------------------------------------------------------------------
// K2b: s[k] = sum_j Zn[j][k] = sum_j Yt[k][j] * rd[j]
__global__ __launch_bounds__(256) void k_colsum(const _Float16* __restrict__ Yt,
                                                const float* __restrict__ rd,
                                                float* __restrict__ s) {
    const int k = blockIdx.x;
    const int t = threadIdx.x;
    const _Float16* yp = Yt + (size_t)k * Nn + t * 32;
    const float*    rp = rd + t * 32;
    float acc = 0.f;
    #pragma unroll
    for (int i = 0; i < 32; ++i) acc += (float)yp[i] * rp[i];
    #pragma unroll
    for (int off = 32; off > 0; off >>= 1) acc += __shfl_down(acc, off, 64);
    __shared__ float red[4];
    if ((t & 63) == 0) red[t >> 6] = acc;
    __syncthreads();
    if (t == 0) s[k] = red[0] + red[1] + red[2] + red[3];
}

// ---------------------------------------------------------------------------
// K3: T += sum_{i in I-tile} Y_i . (A[I, Kchunk] @ Y[Kchunk])
// Block: 512 thr = 8 waves (4 M-waves x 2 N-waves). B staged in LDS
// (XOR-slot swizzle, written linearly by global_load_lds from pre-swizzled
// global addresses). acc persists over the whole K-chunk; epilogue once.
__global__ __launch_bounds__(512, 4) void k_main(const float* __restrict__ A,
                                                 const _Float16* __restrict__ Yt,
                                                 const _Float16* __restrict__ Yr,
                                                 float* __restrict__ T) {
    __shared__ _Float16 Ys[Dd * SK];   // [n=256][slot=16 of 8 f16], slot XOR-swizzled

    const int ib = blockIdx.x & (Nn / BM - 1);   // 128 I-tiles
    const int jb = blockIdx.x >> 7;              // 8 K-chunks
    const int I0 = ib * BM;
    const int K0 = jb * KC;
    const int w  = threadIdx.x >> 6;   // 0..7
    const int wr = w >> 1;             // 0..3  (M-wave: rows)
    const int wn = w & 1;              // 0..1  (N-wave: 128-col half)
    const int l  = threadIdx.x & 63;
    const int lr = l & 15;
    const int lk = l >> 4;

    const size_t arow = (size_t)(I0 + wr * 16 + lr) * Nn;

    f32x4 acc[8];
    #pragma unroll
    for (int t = 0; t < 8; ++t) acc[t] = f32x4{0.f, 0.f, 0.f, 0.f};

    // stage: wave w fills Ys rows [w*32, w*32+32), 4 rows (1 KB) per round q.
    // linear LDS dest; source slot pre-swizzled: s = lr ^ (nrow & 15)
    #define STAGE(SC)                                                          \
    {   const int kc = K0 + (SC) * SK;                                         \
        _Pragma("unroll")                                                      \
        for (int q = 0; q < 8; ++q) {                                          \
            const int nrow = w * 32 + q * 4 + lk;                              \
            const int sl   = lr ^ (nrow & 15);                                 \
            __builtin_amdgcn_global_load_lds(                                  \
                (const __attribute__((address_space(1))) unsigned int*)        \
                    (Yt + (size_t)nrow * Nn + kc + sl * 8),                    \
                (__attribute__((address_space(3))) unsigned int*)              \
                    (Ys + (w * 32 + q * 4) * SK),                              \
                16, 0, 0);                                                     \
        }                                                                      \
    }

    float4 av[8];
    #define LOADA(SC)                                                          \
    {   const float* ab = A + arow + K0 + (SC) * SK + lk * 8;                  \
        _Pragma("unroll")                                                      \
        for (int ks = 0; ks < 4; ++ks) {                                       \
            av[ks*2+0] = *reinterpret_cast<const float4*>(ab + ks * 32);       \
            av[ks*2+1] = *reinterpret_cast<const float4*>(ab + ks * 32 + 4);   \
        }                                                                      \
    }

    LOADA(0);
    STAGE(0);
    asm volatile("s_waitcnt vmcnt(0)" ::: "memory");
    __syncthreads();

    for (int sc = 0; sc < KC / SK; ++sc) {
        // convert prefetched A to fragments
        f16x8 af[4];
        #pragma unroll
        for (int ks = 0; ks < 4; ++ks) {
            const float4 a0 = av[ks*2+0], a1 = av[ks*2+1];
            af[ks] = f16x8{ (_Float16)a0.x, (_Float16)a0.y, (_Float16)a0.z, (_Float16)a0.w,
                            (_Float16)a1.x, (_Float16)a1.y, (_Float16)a1.z, (_Float16)a1.w };
        }
        if (sc < KC / SK - 1) LOADA(sc + 1);   // next A in flight under compute

        #pragma unroll
        for (int tn = 0; tn < 8; ++tn) {
            const int n = wn * 128 + tn * 16 + lr;
            #pragma unroll
            for (int ks = 0; ks < 4; ++ks) {
                const int sl = (ks * 4 + lk) ^ lr;   // ^ (n & 15) == ^ lr
                const f16x8 bf = *reinterpret_cast<const f16x8*>(Ys + n * SK + sl * 8);
                acc[tn] = __builtin_amdgcn_mfma_f32_16x16x32_f16(af[ks], bf, acc[tn], 0, 0, 0);
            }
        }
        __syncthreads();                        // Ys consumed
        if (sc < KC / SK - 1) {
            STAGE(sc + 1);
            asm volatile("s_waitcnt vmcnt(0)" ::: "memory");
            __syncthreads();
        }
    }

    // epilogue: part = sum over held W[i][n] * Y[i][n]
    float part = 0.f;
    #pragma unroll
    for (int tn = 0; tn < 8; ++tn) {
        const int n = wn * 128 + tn * 16 + lr;
        #pragma unroll
        for (int r = 0; r < 4; ++r) {
            const int i = I0 + wr * 16 + lk * 4 + r;
            part += acc[tn][r] * (float)Yr[(size_t)i * Dd + n];
        }
    }
    #pragma unroll
    for (int off = 32; off > 0; off >>= 1) part += __shfl_down(part, off, 64);
    __shared__ float red[8];
    if (l == 0) red[w] = part;
    __syncthreads();
    if (threadIdx.x == 0) {
        float t = 0.f;
        #pragma unroll
        for (int i = 0; i < 8; ++i) t += red[i];
        atomicAdd(T, t);
    }
}

// ---------------------------------------------------------------------------
// K4: out[0] = homo = -T ; out[1] = hetero = ||s||^2 - T
__global__ __launch_bounds__(256) void k_final(const float* __restrict__ s,
                                               const float* __restrict__ T,
                                               float* __restrict__ out) {
    const int t = threadIdx.x;
    float v = s[t];
    float p = v * v;
    #pragma unroll
    for (int off = 32; off > 0; off >>= 1) p += __shfl_down(p, off, 64);
    __shared__ float red[4];
    if ((t & 63) == 0) red[t >> 6] = p;
    __syncthreads();
    if (t == 0) {
        const float ss = red[0] + red[1] + red[2] + red[3];
        const float Tv = *T;
        out[0] = -Tv;
        out[1] = ss - Tv;
    }
}

// ---------------------------------------------------------------------------
extern "C" void kernel_launch(void* const* d_in, const int* in_sizes, int n_in,
                              void* d_out, int out_size, void* d_ws, size_t ws_size,
                              hipStream_t stream) {
    const float* Z = (const float*)d_in[1];
    const float* A = (const float*)d_in[2];
    float* out = (float*)d_out;

    char* ws = (char*)d_ws;
    float*    dis = (float*)(ws);                      // 32 KB
    float*    rd  = (float*)(ws + 32768);              // 32 KB
    float*    s   = (float*)(ws + 65536);              // 1 KB
    float*    T   = (float*)(ws + 66560);              // 4 B
    _Float16* Yt  = (_Float16*)(ws + 131072);          // 4 MB  [256][8192]
    _Float16* Yr  = (_Float16*)(ws + 131072 + (size_t)Nn * Dd * 2);  // 4 MB [8192][256]

    hipMemsetAsync(T, 0, sizeof(float), stream);
    k_rowsum<<<Nn / 4, 256, 0, stream>>>(A, dis, rd);
    k_makeYt<<<Nn / 64, 256, 0, stream>>>(Z, dis, Yt, Yr);
    k_colsum<<<Dd, 256, 0, stream>>>(Yt, rd, s);
    k_main<<<(Nn / BM) * (Nn / KC), 512, 0, stream>>>(A, Yt, Yr, T);
    k_final<<<1, 256, 0, stream>>>(s, T, out);
}

// Round 3
// 151.134 us; speedup vs baseline: 2.6784x; 1.0128x over previous
//
#include <hip/hip_runtime.h>
#include <hip/hip_fp16.h>

typedef _Float16 f16x8 __attribute__((ext_vector_type(8)));
typedef _Float16 f16x4 __attribute__((ext_vector_type(4)));
typedef float    f32x4 __attribute__((ext_vector_type(4)));

constexpr int Nn = 8192;
constexpr int Dd = 256;

constexpr int BM = 64;     // I-rows per block
constexpr int KC = 1024;   // K range per block
constexpr int SK = 64;     // staged K subchunk; LDS buf = 256 n x 64 k f16 = 32 KB
constexpr int NSC = KC / SK;   // 16 subchunks

// ---------------------------------------------------------------------------
// K1: row sums of A -> dis[i] = rsqrt(sum+1e-10), rd[i] = sqrt(sum+1e-10)
//     also zeroes the T accumulator (ws is poisoned 0xAA before timing).
__global__ __launch_bounds__(256) void k_rowsum(const float* __restrict__ A,
                                                float* __restrict__ dis,
                                                float* __restrict__ rd,
                                                float* __restrict__ T) {
    if (blockIdx.x == 0 && threadIdx.x == 0) *T = 0.f;
    const int row  = blockIdx.x * 4 + (threadIdx.x >> 6);
    const int lane = threadIdx.x & 63;
    const float4* rp = reinterpret_cast<const float4*>(A + (size_t)row * Nn);
    float s = 0.f;
    #pragma unroll
    for (int i = 0; i < Nn / 256; ++i) {
        float4 v = rp[i * 64 + lane];
        s += (v.x + v.y) + (v.z + v.w);
    }
    #pragma unroll
    for (int off = 32; off > 0; off >>= 1) s += __shfl_down(s, off, 64);
    if (lane == 0) {
        float rs = s + 1e-10f;
        dis[row] = rsqrtf(rs);
        rd[row]  = sqrtf(rs);
    }
}

// ---------------------------------------------------------------------------
// K2: Y = dis * Z/||Z||; store Yt[256 n][8192 i] (k-major) and Yr[8192][256]
__global__ __launch_bounds__(256) void k_makeYt(const float* __restrict__ Z,
                                               const float* __restrict__ dis,
                                               _Float16* __restrict__ Yt,
                                               _Float16* __restrict__ Yr) {
    __shared__ float nrm[64][4];
    __shared__ _Float16 tile[Dd][72];
    const int t = threadIdx.x;
    const int r = t >> 2, q = t & 3;
    const int row = blockIdx.x * 64 + r;
    const float4* zp = reinterpret_cast<const float4*>(Z + (size_t)row * Dd + q * 64);
    float4 v[16];
    float ss = 0.f;
    #pragma unroll
    for (int i = 0; i < 16; ++i) {
        v[i] = zp[i];
        ss += v[i].x*v[i].x + v[i].y*v[i].y + v[i].z*v[i].z + v[i].w*v[i].w;
    }
    nrm[r][q] = ss;
    __syncthreads();
    const float tot   = nrm[r][0] + nrm[r][1] + nrm[r][2] + nrm[r][3];
    const float scale = dis[row] / fmaxf(sqrtf(tot), 1e-12f);
    #pragma unroll
    for (int i = 0; i < 16; ++i) {
        const int c0 = q * 64 + i * 4;
        f16x4 y = { (_Float16)(v[i].x * scale), (_Float16)(v[i].y * scale),
                    (_Float16)(v[i].z * scale), (_Float16)(v[i].w * scale) };
        tile[c0+0][r] = y[0];
        tile[c0+1][r] = y[1];
        tile[c0+2][r] = y[2];
        tile[c0+3][r] = y[3];
        *reinterpret_cast<f16x4*>(Yr + (size_t)row * Dd + c0) = y;
    }
    __syncthreads();
    int4*       dst = reinterpret_cast<int4*>(Yt + (size_t)t * Nn + blockIdx.x * 64);
    const int4* src = reinterpret_cast<const int4*>(&tile[t][0]);
    #pragma unroll
    for (int i = 0; i < 8; ++i) dst[i] = src[i];
}

// ---------------------------------------------------------------------------
// K2b: s[k] = sum_j Zn[j][k] = sum_j Yt[k][j] * rd[j]
__global__ __launch_bounds__(256) void k_colsum(const _Float16* __restrict__ Yt,
                                                const float* __restrict__ rd,
                                                float* __restrict__ s) {
    const int k = blockIdx.x;
    const int t = threadIdx.x;
    const _Float16* yp = Yt + (size_t)k * Nn + t * 32;
    const float*    rp = rd + t * 32;
    float acc = 0.f;
    #pragma unroll
    for (int i = 0; i < 32; ++i) acc += (float)yp[i] * rp[i];
    #pragma unroll
    for (int off = 32; off > 0; off >>= 1) acc += __shfl_down(acc, off, 64);
    __shared__ float red[4];
    if ((t & 63) == 0) red[t >> 6] = acc;
    __syncthreads();
    if (t == 0) s[k] = red[0] + red[1] + red[2] + red[3];
}

// ---------------------------------------------------------------------------
// K3: T += sum_{i in I-tile} Y_i . (A[I, Kchunk] @ Y[Kchunk])
// 512 thr = 8 waves (4 M x 2 N). Double-buffered LDS (2 x 32 KB), 2-phase
// pipeline with counted vmcnt + raw s_barrier (no full drain in the loop).
__global__ __launch_bounds__(512, 4) void k_main(const float* __restrict__ A,
                                                 const _Float16* __restrict__ Yt,
                                                 const _Float16* __restrict__ Yr,
                                                 float* __restrict__ T) {
    __shared__ _Float16 Ys[2 * Dd * SK];   // [buf][n=256][8 slots of 8 f16], XOR-swizzled

    const int ib = blockIdx.x & (Nn / BM - 1);   // 128 I-tiles
    const int jb = blockIdx.x >> 7;              // 8 K-chunks
    const int I0 = ib * BM;
    const int K0 = jb * KC;
    const int w  = threadIdx.x >> 6;   // 0..7
    const int wr = w >> 1;             // 0..3  (M-wave)
    const int wn = w & 1;              // 0..1  (N-half)
    const int l  = threadIdx.x & 63;
    const int lr = l & 15;
    const int lk = l >> 4;

    const size_t arow = (size_t)(I0 + wr * 16 + lr) * Nn;

    f32x4 acc[8];
    #pragma unroll
    for (int t = 0; t < 8; ++t) acc[t] = f32x4{0.f, 0.f, 0.f, 0.f};

    // Stage one 32 KB subchunk into buffer BUF. Wave w covers rows
    // [w*32, w*32+32), 1 KB (8 rows) per q. Linear LDS dest (base+lane*16);
    // global source slot pre-swizzled: LDS(n, sl) holds global slot sl^(n&7).
    #define STAGE(SC, BUF)                                                     \
    {   const int kc = K0 + (SC) * SK;                                         \
        _Pragma("unroll")                                                      \
        for (int q = 0; q < 4; ++q) {                                          \
            const int nrow = w * 32 + q * 8 + (l >> 3);                        \
            const int s8   = (l & 7) ^ (l >> 3);                               \
            __builtin_amdgcn_global_load_lds(                                  \
                (const __attribute__((address_space(1))) unsigned int*)        \
                    (Yt + (size_t)nrow * Nn + kc + s8 * 8),                    \
                (__attribute__((address_space(3))) unsigned int*)              \
                    (Ys + (BUF) * (Dd * SK) + (w * 32 + q * 8) * SK),          \
                16, 0, 0);                                                     \
        }                                                                      \
    }

    float4 av[4];
    #define LOADA(SC)                                                          \
    {   const float* ab = A + arow + K0 + (SC) * SK + lk * 8;                  \
        av[0] = *reinterpret_cast<const float4*>(ab);                          \
        av[1] = *reinterpret_cast<const float4*>(ab + 4);                      \
        av[2] = *reinterpret_cast<const float4*>(ab + 32);                     \
        av[3] = *reinterpret_cast<const float4*>(ab + 36);                     \
    }

    STAGE(0, 0);
    LOADA(0);
    asm volatile("s_waitcnt vmcnt(0)" ::: "memory");
    __builtin_amdgcn_s_barrier();

    for (int sc = 0; sc < NSC; ++sc) {
        const int cur = sc & 1;
        // convert prefetched A (compiler inserts the exact vmcnt for av here;
        // at this point only the 4 av loads are outstanding)
        f16x8 af[2];
        #pragma unroll
        for (int ks = 0; ks < 2; ++ks) {
            const float4 a0 = av[ks*2], a1 = av[ks*2+1];
            af[ks] = f16x8{ (_Float16)a0.x, (_Float16)a0.y, (_Float16)a0.z, (_Float16)a0.w,
                            (_Float16)a1.x, (_Float16)a1.y, (_Float16)a1.z, (_Float16)a1.w };
        }
        if (sc + 1 < NSC) {
            STAGE(sc + 1, cur ^ 1);     // 4 gload_lds in flight under MFMA
            LOADA(sc + 1);              // 4 A-loads in flight across barrier
        }
        #pragma unroll
        for (int tn = 0; tn < 8; ++tn) {
            const int n = wn * 128 + tn * 16 + lr;
            #pragma unroll
            for (int ks = 0; ks < 2; ++ks) {
                const int sl = (ks * 4 + lk) ^ (lr & 7);
                const f16x8 bf = *reinterpret_cast<const f16x8*>(
                    Ys + cur * (Dd * SK) + n * SK + sl * 8);
                acc[tn] = __builtin_amdgcn_mfma_f32_16x16x32_f16(af[ks], bf, acc[tn], 0, 0, 0);
            }
        }
        if (sc + 1 < NSC) {
            // drain only the staging writes; the 4 A-loads stay outstanding
            asm volatile("s_waitcnt vmcnt(4)" ::: "memory");
            __builtin_amdgcn_s_barrier();
        }
    }

    // epilogue: part = sum over held W[i][n] * Y[i][n]
    float part = 0.f;
    #pragma unroll
    for (int tn = 0; tn < 8; ++tn) {
        const int n = wn * 128 + tn * 16 + lr;
        #pragma unroll
        for (int r = 0; r < 4; ++r) {
            const int i = I0 + wr * 16 + lk * 4 + r;
            part += acc[tn][r] * (float)Yr[(size_t)i * Dd + n];
        }
    }
    #pragma unroll
    for (int off = 32; off > 0; off >>= 1) part += __shfl_down(part, off, 64);
    __shared__ float red[8];
    if (l == 0) red[w] = part;
    __syncthreads();
    if (threadIdx.x == 0) {
        float t = 0.f;
        #pragma unroll
        for (int i = 0; i < 8; ++i) t += red[i];
        atomicAdd(T, t);
    }
}

// ---------------------------------------------------------------------------
// K4: out[0] = homo = -T ; out[1] = hetero = ||s||^2 - T
__global__ __launch_bounds__(256) void k_final(const float* __restrict__ s,
                                               const float* __restrict__ T,
                                               float* __restrict__ out) {
    const int t = threadIdx.x;
    float v = s[t];
    float p = v * v;
    #pragma unroll
    for (int off = 32; off > 0; off >>= 1) p += __shfl_down(p, off, 64);
    __shared__ float red[4];
    if ((t & 63) == 0) red[t >> 6] = p;
    __syncthreads();
    if (t == 0) {
        const float ss = red[0] + red[1] + red[2] + red[3];
        const float Tv = *T;
        out[0] = -Tv;
        out[1] = ss - Tv;
    }
}

// ---------------------------------------------------------------------------
extern "C" void kernel_launch(void* const* d_in, const int* in_sizes, int n_in,
                              void* d_out, int out_size, void* d_ws, size_t ws_size,
                              hipStream_t stream) {
    const float* Z = (const float*)d_in[1];
    const float* A = (const float*)d_in[2];
    float* out = (float*)d_out;

    char* ws = (char*)d_ws;
    float*    dis = (float*)(ws);                      // 32 KB
    float*    rd  = (float*)(ws + 32768);              // 32 KB
    float*    s   = (float*)(ws + 65536);              // 1 KB
    float*    T   = (float*)(ws + 66560);              // 4 B
    _Float16* Yt  = (_Float16*)(ws + 131072);          // 4 MB  [256][8192]
    _Float16* Yr  = (_Float16*)(ws + 131072 + (size_t)Nn * Dd * 2);  // 4 MB [8192][256]

    k_rowsum<<<Nn / 4, 256, 0, stream>>>(A, dis, rd, T);
    k_makeYt<<<Nn / 64, 256, 0, stream>>>(Z, dis, Yt, Yr);
    k_colsum<<<Dd, 256, 0, stream>>>(Yt, rd, s);
    k_main<<<(Nn / BM) * (Nn / KC), 512, 0, stream>>>(A, Yt, Yr, T);
    k_final<<<1, 256, 0, stream>>>(s, T, out);
}

// Round 4
// 148.190 us; speedup vs baseline: 2.7316x; 1.0199x over previous
//
#include <hip/hip_runtime.h>
#include <hip/hip_fp16.h>

typedef _Float16 f16x8  __attribute__((ext_vector_type(8)));
typedef _Float16 f16x4  __attribute__((ext_vector_type(4)));
typedef float    f32x16 __attribute__((ext_vector_type(16)));

constexpr int Nn = 8192;
constexpr int Dd = 256;

constexpr int BM = 64;     // I-rows per block
constexpr int KC = 1024;   // K range per block
constexpr int SK = 64;     // staged K subchunk; LDS buf = 256 n x 64 k f16 = 32 KB
constexpr int NSC = KC / SK;   // 16 subchunks

// ---------------------------------------------------------------------------
// K1: row sums of A -> dis[i] = rsqrt(sum+1e-10), rd[i] = sqrt(sum+1e-10)
//     also zeroes the T accumulator (ws is poisoned 0xAA before timing).
__global__ __launch_bounds__(256) void k_rowsum(const float* __restrict__ A,
                                                float* __restrict__ dis,
                                                float* __restrict__ rd,
                                                float* __restrict__ T) {
    if (blockIdx.x == 0 && threadIdx.x == 0) *T = 0.f;
    const int row  = blockIdx.x * 4 + (threadIdx.x >> 6);
    const int lane = threadIdx.x & 63;
    const float4* rp = reinterpret_cast<const float4*>(A + (size_t)row * Nn);
    float s = 0.f;
    #pragma unroll
    for (int i = 0; i < Nn / 256; ++i) {
        float4 v = rp[i * 64 + lane];
        s += (v.x + v.y) + (v.z + v.w);
    }
    #pragma unroll
    for (int off = 32; off > 0; off >>= 1) s += __shfl_down(s, off, 64);
    if (lane == 0) {
        float rs = s + 1e-10f;
        dis[row] = rsqrtf(rs);
        rd[row]  = sqrtf(rs);
    }
}

// ---------------------------------------------------------------------------
// K2: Y = dis * Z/||Z||; store Yt[256 n][8192 i] (k-major) and Yr[8192][256]
__global__ __launch_bounds__(256) void k_makeYt(const float* __restrict__ Z,
                                               const float* __restrict__ dis,
                                               _Float16* __restrict__ Yt,
                                               _Float16* __restrict__ Yr) {
    __shared__ float nrm[64][4];
    __shared__ _Float16 tile[Dd][72];
    const int t = threadIdx.x;
    const int r = t >> 2, q = t & 3;
    const int row = blockIdx.x * 64 + r;
    const float4* zp = reinterpret_cast<const float4*>(Z + (size_t)row * Dd + q * 64);
    float4 v[16];
    float ss = 0.f;
    #pragma unroll
    for (int i = 0; i < 16; ++i) {
        v[i] = zp[i];
        ss += v[i].x*v[i].x + v[i].y*v[i].y + v[i].z*v[i].z + v[i].w*v[i].w;
    }
    nrm[r][q] = ss;
    __syncthreads();
    const float tot   = nrm[r][0] + nrm[r][1] + nrm[r][2] + nrm[r][3];
    const float scale = dis[row] / fmaxf(sqrtf(tot), 1e-12f);
    #pragma unroll
    for (int i = 0; i < 16; ++i) {
        const int c0 = q * 64 + i * 4;
        f16x4 y = { (_Float16)(v[i].x * scale), (_Float16)(v[i].y * scale),
                    (_Float16)(v[i].z * scale), (_Float16)(v[i].w * scale) };
        tile[c0+0][r] = y[0];
        tile[c0+1][r] = y[1];
        tile[c0+2][r] = y[2];
        tile[c0+3][r] = y[3];
        *reinterpret_cast<f16x4*>(Yr + (size_t)row * Dd + c0) = y;
    }
    __syncthreads();
    int4*       dst = reinterpret_cast<int4*>(Yt + (size_t)t * Nn + blockIdx.x * 64);
    const int4* src = reinterpret_cast<const int4*>(&tile[t][0]);
    #pragma unroll
    for (int i = 0; i < 8; ++i) dst[i] = src[i];
}

// ---------------------------------------------------------------------------
// K2b: s[k] = sum_j Zn[j][k] = sum_j Yt[k][j] * rd[j]
__global__ __launch_bounds__(256) void k_colsum(const _Float16* __restrict__ Yt,
                                                const float* __restrict__ rd,
                                                float* __restrict__ s) {
    const int k = blockIdx.x;
    const int t = threadIdx.x;
    const _Float16* yp = Yt + (size_t)k * Nn + t * 32;
    const float*    rp = rd + t * 32;
    float acc = 0.f;
    #pragma unroll
    for (int i = 0; i < 32; ++i) acc += (float)yp[i] * rp[i];
    #pragma unroll
    for (int off = 32; off > 0; off >>= 1) acc += __shfl_down(acc, off, 64);
    __shared__ float red[4];
    if ((t & 63) == 0) red[t >> 6] = acc;
    __syncthreads();
    if (t == 0) s[k] = red[0] + red[1] + red[2] + red[3];
}

// ---------------------------------------------------------------------------
// K3: T += sum_{i in I-tile} Y_i . (A[I, Kchunk] @ Y[Kchunk])   [32x32x16 MFMA]
// 512 thr = 8 waves: wm = w&1 (32-row half), wn = (w>>1)&1 (128-col half),
// wk = w>>2 (32-k half of each subchunk). k-split partial accs are valid
// because the final reduction  T = sum W[i][n]*Y[i][n]  is linear in W.
// MFMA 32x32x16_f16 layouts (m74/m101, dtype-indep):
//   A: row=l&31, k=(l>>5)*8+e ; B: col=l&31, same k ;
//   D: col=l&31, row=(reg&3)+8*(reg>>2)+4*(l>>5), reg 0..15.
__global__ __launch_bounds__(512, 4) void k_main(const float* __restrict__ A,
                                                 const _Float16* __restrict__ Yt,
                                                 const _Float16* __restrict__ Yr,
                                                 float* __restrict__ T) {
    __shared__ _Float16 Ys[2 * Dd * SK];   // [buf][n=256][8 slots of 8 f16], XOR-swizzled

    const int ib = blockIdx.x & (Nn / BM - 1);   // 128 I-tiles
    const int jb = blockIdx.x >> 7;              // 8 K-chunks
    const int I0 = ib * BM;
    const int K0 = jb * KC;
    const int w   = threadIdx.x >> 6;  // 0..7
    const int wm  = w & 1;             // 32-row half
    const int wn  = (w >> 1) & 1;      // 128-col half
    const int wk  = w >> 2;            // 32-k half of subchunk
    const int l   = threadIdx.x & 63;
    const int ln  = l & 31;
    const int lkh = l >> 5;

    const size_t arow = (size_t)(I0 + wm * 32 + ln) * Nn;
    const int    koff = wk * 32 + lkh * 8;       // lane's k-offset within subchunk

    f32x16 acc[4];
    #pragma unroll
    for (int t = 0; t < 4; ++t) acc[t] = (f32x16)(0.f);

    // Stage one 32 KB subchunk into buffer BUF. Wave w covers rows
    // [w*32, w*32+32), 1 KB (8 rows) per q. Linear LDS dest; global source
    // slot pre-swizzled: LDS(n, t) holds global slot t^(n&7).
    #define STAGE(SC, BUF)                                                     \
    {   const int kc = K0 + (SC) * SK;                                         \
        _Pragma("unroll")                                                      \
        for (int q = 0; q < 4; ++q) {                                          \
            const int nrow = w * 32 + q * 8 + (l >> 3);                        \
            const int s8   = (l & 7) ^ (l >> 3);                               \
            __builtin_amdgcn_global_load_lds(                                  \
                (const __attribute__((address_space(1))) unsigned int*)        \
                    (Yt + (size_t)nrow * Nn + kc + s8 * 8),                    \
                (__attribute__((address_space(3))) unsigned int*)              \
                    (Ys + (BUF) * (Dd * SK) + (w * 32 + q * 8) * SK),          \
                16, 0, 0);                                                     \
        }                                                                      \
    }

    float4 av[4];
    #define LOADA(SC)                                                          \
    {   const float* ab = A + arow + K0 + (SC) * SK + koff;                    \
        av[0] = *reinterpret_cast<const float4*>(ab);                          \
        av[1] = *reinterpret_cast<const float4*>(ab + 4);                      \
        av[2] = *reinterpret_cast<const float4*>(ab + 16);                     \
        av[3] = *reinterpret_cast<const float4*>(ab + 20);                     \
    }

    STAGE(0, 0);
    LOADA(0);
    asm volatile("s_waitcnt vmcnt(0)" ::: "memory");
    __builtin_amdgcn_s_barrier();

    for (int sc = 0; sc < NSC; ++sc) {
        const int cur = sc & 1;
        f16x8 af[2];
        #pragma unroll
        for (int ks = 0; ks < 2; ++ks) {
            const float4 a0 = av[ks*2], a1 = av[ks*2+1];
            af[ks] = f16x8{ (_Float16)a0.x, (_Float16)a0.y, (_Float16)a0.z, (_Float16)a0.w,
                            (_Float16)a1.x, (_Float16)a1.y, (_Float16)a1.z, (_Float16)a1.w };
        }
        if (sc + 1 < NSC) {
            STAGE(sc + 1, cur ^ 1);     // 4 gload_lds in flight under MFMA
            LOADA(sc + 1);              // 4 A-loads in flight across barrier
        }
        #pragma unroll
        for (int tn = 0; tn < 4; ++tn) {
            const int n = wn * 128 + tn * 32 + ln;
            #pragma unroll
            for (int ks = 0; ks < 2; ++ks) {
                const int sl = (wk * 4 + ks * 2 + lkh) ^ (n & 7);
                const f16x8 bf = *reinterpret_cast<const f16x8*>(
                    Ys + cur * (Dd * SK) + n * SK + sl * 8);
                acc[tn] = __builtin_amdgcn_mfma_f32_32x32x16_f16(af[ks], bf, acc[tn], 0, 0, 0);
            }
        }
        if (sc + 1 < NSC) {
            // drain only the staging writes; the 4 A-loads stay outstanding
            asm volatile("s_waitcnt vmcnt(4)" ::: "memory");
            __builtin_amdgcn_s_barrier();
        }
    }

    // epilogue: part = sum over held W[i][n] * Y[i][n]
    float part = 0.f;
    #pragma unroll
    for (int tn = 0; tn < 4; ++tn) {
        const int n = wn * 128 + tn * 32 + ln;
        #pragma unroll
        for (int r = 0; r < 16; ++r) {
            const int i = I0 + wm * 32 + (r & 3) + 8 * (r >> 2) + 4 * lkh;
            part += acc[tn][r] * (float)Yr[(size_t)i * Dd + n];
        }
    }
    #pragma unroll
    for (int off = 32; off > 0; off >>= 1) part += __shfl_down(part, off, 64);
    __shared__ float red[8];
    if (l == 0) red[w] = part;
    __syncthreads();
    if (threadIdx.x == 0) {
        float t = 0.f;
        #pragma unroll
        for (int i = 0; i < 8; ++i) t += red[i];
        atomicAdd(T, t);
    }
}

// ---------------------------------------------------------------------------
// K4: out[0] = homo = -T ; out[1] = hetero = ||s||^2 - T
__global__ __launch_bounds__(256) void k_final(const float* __restrict__ s,
                                               const float* __restrict__ T,
                                               float* __restrict__ out) {
    const int t = threadIdx.x;
    float v = s[t];
    float p = v * v;
    #pragma unroll
    for (int off = 32; off > 0; off >>= 1) p += __shfl_down(p, off, 64);
    __shared__ float red[4];
    if ((t & 63) == 0) red[t >> 6] = p;
    __syncthreads();
    if (t == 0) {
        const float ss = red[0] + red[1] + red[2] + red[3];
        const float Tv = *T;
        out[0] = -Tv;
        out[1] = ss - Tv;
    }
}

// ---------------------------------------------------------------------------
extern "C" void kernel_launch(void* const* d_in, const int* in_sizes, int n_in,
                              void* d_out, int out_size, void* d_ws, size_t ws_size,
                              hipStream_t stream) {
    const float* Z = (const float*)d_in[1];
    const float* A = (const float*)d_in[2];
    float* out = (float*)d_out;

    char* ws = (char*)d_ws;
    float*    dis = (float*)(ws);                      // 32 KB
    float*    rd  = (float*)(ws + 32768);              // 32 KB
    float*    s   = (float*)(ws + 65536);              // 1 KB
    float*    T   = (float*)(ws + 66560);              // 4 B
    _Float16* Yt  = (_Float16*)(ws + 131072);          // 4 MB  [256][8192]
    _Float16* Yr  = (_Float16*)(ws + 131072 + (size_t)Nn * Dd * 2);  // 4 MB [8192][256]

    k_rowsum<<<Nn / 4, 256, 0, stream>>>(A, dis, rd, T);
    k_makeYt<<<Nn / 64, 256, 0, stream>>>(Z, dis, Yt, Yr);
    k_colsum<<<Dd, 256, 0, stream>>>(Yt, rd, s);
    k_main<<<(Nn / BM) * (Nn / KC), 512, 0, stream>>>(A, Yt, Yr, T);
    k_final<<<1, 256, 0, stream>>>(s, T, out);
}